// Round 10
// baseline (106.920 us; speedup 1.0000x reference)
//
#include <hip/hip_runtime.h>
#include <hip/hip_bf16.h>

#define BATCH 8192
#define DIN   4096
#define H1    128
#define NLAT  512
#define LAT   32
#define BM    16
#define BKW   64            // per-step K columns (per wave)
#define WSTEPS 16           // per-wave K-range 1024 / BKW
#define ABUF  1024          // 16 rows * 64 ushorts per private buffer
#define PPITCH 136          // pacc row pitch (ushorts)

typedef short bf16x8 __attribute__((ext_vector_type(8)));
typedef float f32x4  __attribute__((ext_vector_type(4)));

static __device__ __forceinline__ unsigned short f2bf(float f) {
  union { float f; unsigned u; } v; v.f = f;
  return (unsigned short)((v.u + 0x7FFFu + ((v.u >> 16) & 1u)) >> 16);  // RNE
}
static __device__ __forceinline__ float bf2f(unsigned short u) {
  union { unsigned u; float f; } v; v.u = ((unsigned)u) << 16; return v.f;
}
static __device__ __forceinline__ void cvtw8(unsigned short* p, f32x4 a, f32x4 b) {
  union { bf16x8 v; unsigned short u[8]; } o;
#pragma unroll
  for (int j = 0; j < 4; j++) { o.u[j] = f2bf(a[j]); o.u[4 + j] = f2bf(b[j]); }
  *(bf16x8*)p = o.v;
}

// ---- prep_all: W1 -> W1B frag-packed bf16; W2 -> W2B frag-packed bf16;
// decoders -> decT [32][4096] f32. Fragment packing (gi = k32*NCF + cf):
// elem j of lane (g=lane>>4, fr=lane&15) holds W[k32*32+g*8+j][cf*16+fr],
// so a wave's fragment load is one contiguous 1KB dwordx4. ----
__global__ void prep_all(const float* __restrict__ W1, const float* __restrict__ W2,
                         const float* __restrict__ dec,
                         unsigned short* __restrict__ W1B,
                         unsigned short* __restrict__ W2B,
                         float* __restrict__ decT) {
  int b = blockIdx.x;
  int t = threadIdx.x;
  if (b < 256) {
    int gi = (b << 2) + (t >> 6);         // k32*8 + cf
    int lane = t & 63;
    int kb = ((gi >> 3) << 5) + ((lane >> 4) << 3);
    int c = ((gi & 7) << 4) + (lane & 15);
    union { bf16x8 v; unsigned short u[8]; } o;
#pragma unroll
    for (int j = 0; j < 8; j++) o.u[j] = f2bf(W1[(size_t)(kb + j) * H1 + c]);
    *(bf16x8*)(W1B + (((size_t)gi << 6) + lane) * 8) = o.v;
  } else if (b < 288) {
    int gi = ((b - 256) << 2) + (t >> 6); // k32*32 + cf
    int lane = t & 63;
    int kb = ((gi >> 5) << 5) + ((lane >> 4) << 3);
    int c = ((gi & 31) << 4) + (lane & 15);
    union { bf16x8 v; unsigned short u[8]; } o;
#pragma unroll
    for (int j = 0; j < 8; j++) o.u[j] = f2bf(W2[(size_t)(kb + j) * NLAT + c]);
    *(bf16x8*)(W2B + (((size_t)gi << 6) + lane) * 8) = o.v;
  } else {
    __shared__ float tbuf[32][33];
    int d0 = (b - 288) * 32;
    int tx = t & 31, ty = t >> 5;
#pragma unroll
    for (int i = 0; i < 32; i += 8)
      tbuf[ty + i][tx] = dec[(size_t)(d0 + ty + i) * LAT + tx];
    __syncthreads();
#pragma unroll
    for (int i = 0; i < 32; i += 8)
      decT[(size_t)(ty + i) * DIN + (d0 + tx)] = tbuf[tx][ty + i];
  }
}

// ---- fused_kernel: per 16-row block:
//   A: h = relu(x@W1+b1) — barrier-free wave-private-K (proven R8/R9),
//      partials in bf16 LDS (halves pacc -> ~48 KB total LDS)
//   B: z = h@W2+b2 -> zout; zsum fold -> zs[16][32] in LDS (no global trip)
//   C: recon = zs @ decT -> rout (f32, write-bound)
// Grid 512 x 256 thr -> 2 co-resident blocks/CU: one block's phase-C writes
// overlap the other's phase-A reads (both HBM directions busy). ----
__global__ __launch_bounds__(256, 3) void fused_kernel(
    const float* __restrict__ x, const unsigned short* __restrict__ W1B,
    const unsigned short* __restrict__ W2B,
    const float* __restrict__ b1, const float* __restrict__ b2,
    const float* __restrict__ decT,
    float* __restrict__ zout, float* __restrict__ rout) {
  __shared__ unsigned short Apriv[4 * 2 * ABUF];   // 16 KB per-wave dbuf
  __shared__ unsigned short pacc[4][16][PPITCH];   // 17.4 KB bf16 partials
  __shared__ unsigned short hs[16 * 128];          // 4 KB, XOR-swizzled
  __shared__ float zsp[4][16][33];                 // 8.4 KB
  __shared__ float zs[16][32];                     // 2 KB

  const int t = threadIdx.x;
  const int rbase = blockIdx.x << 4;
  const int w = t >> 6, lane = t & 63;
  const int g = lane >> 4, fr = lane & 15;

  // ---- phase A (barrier-free, depth-2 reg prefetch) ----
  const int srow = lane >> 2, sq = lane & 3;       // 4 lanes/row, 16 f32 each
  const float* xp = x + (size_t)(rbase + srow) * DIN + (w << 10) + (sq << 4);
  unsigned short* abase = Apriv + (w << 11);
  const int wg0 = ((sq << 1) ^ (srow & 7)) << 3;
  const int wg1 = (((sq << 1) | 1) ^ (srow & 7)) << 3;

  f32x4 acc[8];
#pragma unroll
  for (int i = 0; i < 8; i++) acc[i] = (f32x4){0.f, 0.f, 0.f, 0.f};

  f32x4 pA0, pA1, pA2, pA3, pB0, pB1, pB2, pB3;
#define LOADPF(P, S) do {                              \
    const float* np_ = xp + (S) * BKW;                 \
    P##0 = *(const f32x4*)np_;                         \
    P##1 = *(const f32x4*)(np_ + 4);                   \
    P##2 = *(const f32x4*)(np_ + 8);                   \
    P##3 = *(const f32x4*)(np_ + 12);                  \
  } while (0)

  LOADPF(pA, 0);
  LOADPF(pB, 1);
  {
    unsigned short* wr = abase + srow * 64;
    cvtw8(wr + wg0, pA0, pA1);
    cvtw8(wr + wg1, pA2, pA3);
  }

  // STEP(S,PAR,PFW,PFL): issue load S+2 -> PFL; MFMA buf[PAR]; write PFW
  // (data for step S+1) -> buf[PAR^1]. Wave-internal lgkmcnt orders ds ops.
#define STEP(S, PAR, PFW, PFL) do {                                          \
    if ((S) + 2 < WSTEPS) LOADPF(PFL, (S) + 2);                              \
    const unsigned short* ab_ = abase + (PAR) * ABUF;                        \
    const int kbase_ = (w << 5) + ((S) << 1);                                \
    _Pragma("unroll")                                                        \
    for (int k32l = 0; k32l < 2; ++k32l) {                                   \
      bf16x8 a_ = *(const bf16x8*)(ab_ + fr * 64 +                           \
                    ((((k32l << 2) + g) ^ (fr & 7)) << 3));                  \
      const unsigned short* bp_ =                                            \
          W1B + (((size_t)(kbase_ + k32l) << 3) << 9) + (lane << 3);         \
      _Pragma("unroll")                                                      \
      for (int cf = 0; cf < 8; ++cf) {                                       \
        bf16x8 bv_ = *(const bf16x8*)(bp_ + ((size_t)cf << 9));              \
        acc[cf] = __builtin_amdgcn_mfma_f32_16x16x32_bf16(a_, bv_, acc[cf], 0, 0, 0); \
      }                                                                      \
    }                                                                        \
    if ((S) + 1 < WSTEPS) {                                                  \
      unsigned short* wr_ = abase + ((PAR) ^ 1) * ABUF + srow * 64;          \
      cvtw8(wr_ + wg0, PFW##0, PFW##1);                                      \
      cvtw8(wr_ + wg1, PFW##2, PFW##3);                                      \
    }                                                                        \
  } while (0)

  for (int s2 = 0; s2 < WSTEPS; s2 += 2) {
    STEP(s2 + 0, 0, pB, pA);
    STEP(s2 + 1, 1, pA, pB);
  }
#undef STEP
#undef LOADPF

  // partial acc -> pacc (bf16). C/D: col=fr, row=g*4+j.
#pragma unroll
  for (int cf = 0; cf < 8; ++cf)
#pragma unroll
    for (int j = 0; j < 4; ++j)
      pacc[w][(g << 2) + j][(cf << 4) + fr] = f2bf(acc[cf][j]);
  __syncthreads();

  // reduce 4 partials + b1 + relu -> hs (bf16, XOR-swizzled granules)
  {
    const int r = t >> 4, c8 = (t & 15) << 3;
    f32x4 s0, s1;
#pragma unroll
    for (int j = 0; j < 4; j++) { s0[j] = b1[c8 + j]; s1[j] = b1[c8 + 4 + j]; }
#pragma unroll
    for (int wv = 0; wv < 4; ++wv) {
      union { bf16x8 v; unsigned short u[8]; } p;
      p.v = *(const bf16x8*)&pacc[wv][r][c8];
#pragma unroll
      for (int j = 0; j < 4; j++) { s0[j] += bf2f(p.u[j]); s1[j] += bf2f(p.u[4 + j]); }
    }
#pragma unroll
    for (int j = 0; j < 4; j++) { s0[j] = fmaxf(s0[j], 0.f); s1[j] = fmaxf(s1[j], 0.f); }
    cvtw8(hs + (r << 7) + (((t & 15) ^ (r & 15)) << 3), s0, s1);
  }
  __syncthreads();

  // ---- phase B: z = h @ W2 + b2. Wave w: 16 rows x cols w*128..+128. ----
  f32x4 acc2[8];
#pragma unroll
  for (int i = 0; i < 8; i++) acc2[i] = (f32x4){0.f, 0.f, 0.f, 0.f};
#pragma unroll
  for (int k32 = 0; k32 < 4; ++k32) {
    bf16x8 a0 = *(const bf16x8*)(hs + (fr << 7) +
                  ((((k32 << 2) + g) ^ (fr & 15)) << 3));
#pragma unroll
    for (int cc = 0; cc < 8; ++cc) {
      bf16x8 bv = *(const bf16x8*)(W2B +
          (((size_t)((k32 << 5) + (w << 3) + cc)) << 9) + (lane << 3));
      acc2[cc] = __builtin_amdgcn_mfma_f32_16x16x32_bf16(a0, bv, acc2[cc], 0, 0, 0);
    }
  }
  // z write + zsum fold. col = w*128 + cc*16 + fr; latent = (cc&1)*16+fr.
  {
    f32x4 zv[8];
#pragma unroll
    for (int cc = 0; cc < 8; ++cc) {
      const float b2v = b2[(w << 7) + (cc << 4) + fr];
#pragma unroll
      for (int j = 0; j < 4; j++) zv[cc][j] = acc2[cc][j] + b2v;
    }
    const int row0 = g << 2;
#pragma unroll
    for (int j = 0; j < 4; j++) {
#pragma unroll
      for (int cc = 0; cc < 8; ++cc)
        zout[(size_t)(rbase + row0 + j) * NLAT + (w << 7) + (cc << 4) + fr] = zv[cc][j];
      zsp[w][row0 + j][fr]      = zv[0][j] + zv[2][j] + zv[4][j] + zv[6][j];
      zsp[w][row0 + j][16 + fr] = zv[1][j] + zv[3][j] + zv[5][j] + zv[7][j];
    }
  }
  __syncthreads();
  // reduce 4 wave-partials -> zs LDS (deterministic)
#pragma unroll
  for (int i = 0; i < 2; i++) {
    int idx = t + (i << 8);
    int r = idx >> 5, l = idx & 31;
    zs[r][l] = zsp[0][r][l] + zsp[1][r][l] + zsp[2][r][l] + zsp[3][r][l];
  }
  __syncthreads();

  // ---- phase C: recon = zs @ decT. Wave w: 16 rows x cols [w*1024,+1024),
  // 4 passes of 256 cols; a[16] f32x4 static-indexed; zs broadcast reads. ----
#pragma unroll
  for (int pass = 0; pass < 4; ++pass) {
    const int dcol = (w << 10) + (pass << 8) + (lane << 2);
    f32x4 a[16];
#pragma unroll
    for (int r = 0; r < 16; ++r) a[r] = (f32x4){0.f, 0.f, 0.f, 0.f};
#pragma unroll 4
    for (int l = 0; l < 32; ++l) {
      f32x4 dv = *(const f32x4*)(decT + (size_t)l * DIN + dcol);
#pragma unroll
      for (int r = 0; r < 16; ++r) {
        const float zvv = zs[r][l];
#pragma unroll
        for (int j = 0; j < 4; j++) a[r][j] += zvv * dv[j];
      }
    }
#pragma unroll
    for (int r = 0; r < 16; ++r)
      *(f32x4*)(rout + (size_t)(rbase + r) * DIN + dcol) = a[r];
  }
}

extern "C" void kernel_launch(void* const* d_in, const int* in_sizes, int n_in,
                              void* d_out, int out_size, void* d_ws, size_t ws_size,
                              hipStream_t stream) {
  const float* x   = (const float*)d_in[0];
  const float* W1  = (const float*)d_in[1];
  const float* b1  = (const float*)d_in[2];
  const float* W2  = (const float*)d_in[3];
  const float* b2  = (const float*)d_in[4];
  const float* dec = (const float*)d_in[5];
  float* zout = (float*)d_out;
  float* rout = zout + (size_t)BATCH * NLAT;

  char* ws = (char*)d_ws;
  unsigned short* W1B = (unsigned short*)ws;                 // 1 MB
  unsigned short* W2B = (unsigned short*)(ws + (1u << 20));  // 128 KB
  float* decT = (float*)(ws + (1u << 20) + (1u << 17));      // 512 KB

  prep_all<<<dim3(416), 256, 0, stream>>>(W1, W2, dec, W1B, W2B, decT);
  fused_kernel<<<dim3(BATCH / BM), 256, 0, stream>>>(x, W1B, W2B, b1, b2, decT, zout, rout);
}

// Round 11
// 92.091 us; speedup vs baseline: 1.1610x; 1.1610x over previous
//
#include <hip/hip_runtime.h>
#include <hip/hip_bf16.h>

#define BATCH 8192
#define DIN   4096
#define H1    128
#define NLAT  512
#define LAT   32
#define BM    16
#define BKW   64            // per-step K columns (per wave)
#define WSTEPS 8            // per-wave K-range 512 / BKW
#define ABUF  1024          // 16 rows * 64 ushorts per private buffer
#define PP    130           // pacc pitch (ushorts): 128 + 2 (rows offset by 65 banks)

typedef short bf16x8 __attribute__((ext_vector_type(8)));
typedef short bf16x4 __attribute__((ext_vector_type(4)));
typedef float f32x4  __attribute__((ext_vector_type(4)));

static __device__ __forceinline__ unsigned short f2bf(float f) {
  union { float f; unsigned u; } v; v.f = f;
  return (unsigned short)((v.u + 0x7FFFu + ((v.u >> 16) & 1u)) >> 16);  // RNE
}
static __device__ __forceinline__ float bf2f(unsigned short u) {
  union { unsigned u; float f; } v; v.u = ((unsigned)u) << 16; return v.f;
}
static __device__ __forceinline__ void cvtw8(unsigned short* p, f32x4 a, f32x4 b) {
  union { bf16x8 v; unsigned short u[8]; } o;
#pragma unroll
  for (int j = 0; j < 4; j++) { o.u[j] = f2bf(a[j]); o.u[4 + j] = f2bf(b[j]); }
  *(bf16x8*)p = o.v;
}

// ---- prep_all: W1 -> W1B frag-packed bf16; W2 -> W2B frag-packed bf16;
// decoders -> decT [32][4096] f32. (unchanged, verified R4-R10) ----
__global__ void prep_all(const float* __restrict__ W1, const float* __restrict__ W2,
                         const float* __restrict__ dec,
                         unsigned short* __restrict__ W1B,
                         unsigned short* __restrict__ W2B,
                         float* __restrict__ decT) {
  int b = blockIdx.x;
  int t = threadIdx.x;
  if (b < 256) {
    int gi = (b << 2) + (t >> 6);
    int lane = t & 63;
    int kb = ((gi >> 3) << 5) + ((lane >> 4) << 3);
    int c = ((gi & 7) << 4) + (lane & 15);
    union { bf16x8 v; unsigned short u[8]; } o;
#pragma unroll
    for (int j = 0; j < 8; j++) o.u[j] = f2bf(W1[(size_t)(kb + j) * H1 + c]);
    *(bf16x8*)(W1B + (((size_t)gi << 6) + lane) * 8) = o.v;
  } else if (b < 288) {
    int gi = ((b - 256) << 2) + (t >> 6);
    int lane = t & 63;
    int kb = ((gi >> 5) << 5) + ((lane >> 4) << 3);
    int c = ((gi & 31) << 4) + (lane & 15);
    union { bf16x8 v; unsigned short u[8]; } o;
#pragma unroll
    for (int j = 0; j < 8; j++) o.u[j] = f2bf(W2[(size_t)(kb + j) * NLAT + c]);
    *(bf16x8*)(W2B + (((size_t)gi << 6) + lane) * 8) = o.v;
  } else {
    __shared__ float tbuf[32][33];
    int d0 = (b - 288) * 32;
    int tx = t & 31, ty = t >> 5;
#pragma unroll
    for (int i = 0; i < 32; i += 8)
      tbuf[ty + i][tx] = dec[(size_t)(d0 + ty + i) * LAT + tx];
    __syncthreads();
#pragma unroll
    for (int i = 0; i < 32; i += 8)
      decT[(size_t)(ty + i) * DIN + (d0 + tx)] = tbuf[tx][ty + i];
  }
}

// ---- enc_kernel: h = relu(x@W1+b1); z = h@W2+b2 -> zout; zsum -> zsumg.
// OCCUPANCY EXPERIMENT: 8 waves x wave-private K-split 8 (K=512/wave, 8
// steps), BM=16, grid 512 -> 2 blocks/CU x 8 waves = 16 waves/CU (4/SIMD),
// 2x all prior variants. LDS 68.5 KB via manual layout; zsp aliases the
// dead Apriv region. Phase A is the verified R8 barrier-free structure. ----
__global__ __launch_bounds__(512, 4) void enc_kernel(
    const float* __restrict__ x, const unsigned short* __restrict__ W1B,
    const unsigned short* __restrict__ W2B,
    const float* __restrict__ b1, const float* __restrict__ b2,
    float* __restrict__ zout, float* __restrict__ zsumg) {
  // [0,32768): Apriv 8 waves x 2 bufs x 1024 ushorts   (phase A; dies at bar1)
  // [32768,66048): pacc bf16 [8][16][PP=130]           (dies at bar2)
  // [66048,70144): hs bf16 16x128, XOR-swizzled granules
  // zsp f32 [8][16][33] aliases [0,16896)              (phase B epilogue)
  __shared__ __align__(16) unsigned char smem[70144];
  unsigned short* Apriv = (unsigned short*)smem;
  unsigned short* pacc  = (unsigned short*)(smem + 32768);
  unsigned short* hs    = (unsigned short*)(smem + 66048);
  float* zsp            = (float*)smem;

  const int t = threadIdx.x;
  const int rbase = blockIdx.x << 4;
  const int w = t >> 6, lane = t & 63;
  const int g = lane >> 4, fr = lane & 15;

  // ---- phase A (barrier-free, wave-private K = [w*512, w*512+512)) ----
  const int srow = lane >> 2, sq = lane & 3;      // 4 lanes/row, 16 f32 each
  const float* xp = x + (size_t)(rbase + srow) * DIN + (w << 9) + (sq << 4);
  unsigned short* abase = Apriv + (w << 11);
  const int wg0 = ((sq << 1) ^ (srow & 7)) << 3;
  const int wg1 = (((sq << 1) | 1) ^ (srow & 7)) << 3;

  f32x4 acc[8];
#pragma unroll
  for (int i = 0; i < 8; i++) acc[i] = (f32x4){0.f, 0.f, 0.f, 0.f};

  f32x4 pA0, pA1, pA2, pA3, pB0, pB1, pB2, pB3;
#define LOADPF(P, S) do {                              \
    const float* np_ = xp + (S) * BKW;                 \
    P##0 = *(const f32x4*)np_;                         \
    P##1 = *(const f32x4*)(np_ + 4);                   \
    P##2 = *(const f32x4*)(np_ + 8);                   \
    P##3 = *(const f32x4*)(np_ + 12);                  \
  } while (0)

  LOADPF(pA, 0);
  LOADPF(pB, 1);
  {
    unsigned short* wr = abase + srow * 64;
    cvtw8(wr + wg0, pA0, pA1);
    cvtw8(wr + wg1, pA2, pA3);
  }

#define STEP(S, PAR, PFW, PFL) do {                                          \
    if ((S) + 2 < WSTEPS) LOADPF(PFL, (S) + 2);                              \
    const unsigned short* ab_ = abase + (PAR) * ABUF;                        \
    const int kbase_ = (w << 4) + ((S) << 1);                                \
    _Pragma("unroll")                                                        \
    for (int k32l = 0; k32l < 2; ++k32l) {                                   \
      bf16x8 a_ = *(const bf16x8*)(ab_ + fr * 64 +                           \
                    ((((k32l << 2) + g) ^ (fr & 7)) << 3));                  \
      const unsigned short* bp_ =                                            \
          W1B + (((size_t)(kbase_ + k32l) << 3) << 9) + (lane << 3);         \
      _Pragma("unroll")                                                      \
      for (int cf = 0; cf < 8; ++cf) {                                       \
        bf16x8 bv_ = *(const bf16x8*)(bp_ + ((size_t)cf << 9));              \
        acc[cf] = __builtin_amdgcn_mfma_f32_16x16x32_bf16(a_, bv_, acc[cf], 0, 0, 0); \
      }                                                                      \
    }                                                                        \
    if ((S) + 1 < WSTEPS) {                                                  \
      unsigned short* wr_ = abase + ((PAR) ^ 1) * ABUF + srow * 64;          \
      cvtw8(wr_ + wg0, PFW##0, PFW##1);                                      \
      cvtw8(wr_ + wg1, PFW##2, PFW##3);                                      \
    }                                                                        \
  } while (0)

  for (int s2 = 0; s2 < WSTEPS; s2 += 2) {
    STEP(s2 + 0, 0, pB, pA);
    STEP(s2 + 1, 1, pA, pB);
  }
#undef STEP
#undef LOADPF

  // partial acc -> pacc bf16. C/D: col=fr, row=g*4+j.
#pragma unroll
  for (int cf = 0; cf < 8; ++cf)
#pragma unroll
    for (int j = 0; j < 4; ++j)
      pacc[(w * BM + (g << 2) + j) * PP + (cf << 4) + fr] = f2bf(acc[cf][j]);
  __syncthreads();

  // reduce 8 partials + b1 + relu -> hs (bf16, XOR-swizzled 8-granules).
  // 512 thr: 32/row, 4 cols each.
  {
    const int r = t >> 5, c4 = (t & 31) << 2;
    float s0 = b1[c4], s1 = b1[c4 + 1], s2 = b1[c4 + 2], s3 = b1[c4 + 3];
#pragma unroll
    for (int wv = 0; wv < 8; ++wv) {
      union { bf16x4 v; unsigned short u[4]; } p;
      p.v = *(const bf16x4*)&pacc[(wv * BM + r) * PP + c4];
      s0 += bf2f(p.u[0]); s1 += bf2f(p.u[1]); s2 += bf2f(p.u[2]); s3 += bf2f(p.u[3]);
    }
    union { bf16x4 v; unsigned short u[4]; } o;
    o.u[0] = f2bf(fmaxf(s0, 0.f)); o.u[1] = f2bf(fmaxf(s1, 0.f));
    o.u[2] = f2bf(fmaxf(s2, 0.f)); o.u[3] = f2bf(fmaxf(s3, 0.f));
    const int gi = c4 >> 3;                       // granule 0..15
    *(bf16x4*)(hs + (r << 7) + ((gi ^ (r & 15)) << 3) + (c4 & 7)) = o.v;
  }
  __syncthreads();

  // ---- phase B: z = h @ W2 + b2. Wave w: 16 rows x cols w*64..+64. ----
  f32x4 acc2[4];
#pragma unroll
  for (int i = 0; i < 4; i++) acc2[i] = (f32x4){0.f, 0.f, 0.f, 0.f};
#pragma unroll
  for (int k32 = 0; k32 < 4; ++k32) {
    bf16x8 a0 = *(const bf16x8*)(hs + (fr << 7) +
                  ((((k32 << 2) + g) ^ (fr & 15)) << 3));
#pragma unroll
    for (int cc = 0; cc < 4; ++cc) {
      bf16x8 bv = *(const bf16x8*)(W2B +
          (((size_t)((k32 << 5) + (w << 2) + cc)) << 9) + (lane << 3));
      acc2[cc] = __builtin_amdgcn_mfma_f32_16x16x32_bf16(a0, bv, acc2[cc], 0, 0, 0);
    }
  }
  // z write + zsum fold. col = w*64+cc*16+fr; latent = (cc&1)*16+fr;
  // wave w covers factors 2w (cc 0,2) and 2w+1 (cc 1,3).
  {
    f32x4 zv[4];
#pragma unroll
    for (int cc = 0; cc < 4; ++cc) {
      const float b2v = b2[(w << 6) + (cc << 4) + fr];
#pragma unroll
      for (int j = 0; j < 4; j++) zv[cc][j] = acc2[cc][j] + b2v;
    }
    const int row0 = g << 2;
#pragma unroll
    for (int j = 0; j < 4; j++) {
#pragma unroll
      for (int cc = 0; cc < 4; ++cc)
        zout[(size_t)(rbase + row0 + j) * NLAT + (w << 6) + (cc << 4) + fr] = zv[cc][j];
      zsp[(w * BM + row0 + j) * 33 + fr]      = zv[0][j] + zv[2][j];
      zsp[(w * BM + row0 + j) * 33 + 16 + fr] = zv[1][j] + zv[3][j];
    }
  }
  __syncthreads();
  // reduce 8 wave-partials -> zsumg (512 thr = 16x32 exactly)
  {
    const int r = t >> 5, l = t & 31;
    float s = 0.f;
#pragma unroll
    for (int wv = 0; wv < 8; ++wv) s += zsp[(wv * BM + r) * 33 + l];
    zsumg[(size_t)(rbase + r) * LAT + l] = s;
  }
}

// ---- recon_kernel: rout[b][d] = sum_l zsum[b][l] * decT[l][d]. (unchanged) ----
__global__ __launch_bounds__(256) void recon_kernel(
    const float* __restrict__ zsumg, const float* __restrict__ decT,
    float* __restrict__ rout) {
  __shared__ float zs[32][32];
  int t = threadIdx.x;
  int rbase = (blockIdx.x >> 4) << 5;
  int dcol0 = (blockIdx.x & 15) << 8;
  {
    int r = t >> 3, c4 = (t & 7) << 2;
    *(f32x4*)&zs[r][c4] = *(const f32x4*)(zsumg + (size_t)(rbase + r) * LAT + c4);
  }
  __syncthreads();
  int wq = t >> 6, lane = t & 63;
  int r0 = wq << 3;
  int dcol = dcol0 + (lane << 2);
  f32x4 acc[8];
#pragma unroll
  for (int r = 0; r < 8; r++) acc[r] = (f32x4){0.f, 0.f, 0.f, 0.f};
#pragma unroll 4
  for (int l = 0; l < 32; l++) {
    f32x4 dv = *(const f32x4*)(decT + (size_t)l * DIN + dcol);
#pragma unroll
    for (int r = 0; r < 8; r++) {
      float zv = zs[r0 + r][l];
#pragma unroll
      for (int j = 0; j < 4; j++) acc[r][j] += zv * dv[j];
    }
  }
#pragma unroll
  for (int r = 0; r < 8; r++)
    *(f32x4*)(rout + (size_t)(rbase + r0 + r) * DIN + dcol) = acc[r];
}

extern "C" void kernel_launch(void* const* d_in, const int* in_sizes, int n_in,
                              void* d_out, int out_size, void* d_ws, size_t ws_size,
                              hipStream_t stream) {
  const float* x   = (const float*)d_in[0];
  const float* W1  = (const float*)d_in[1];
  const float* b1  = (const float*)d_in[2];
  const float* W2  = (const float*)d_in[3];
  const float* b2  = (const float*)d_in[4];
  const float* dec = (const float*)d_in[5];
  float* zout = (float*)d_out;
  float* rout = zout + (size_t)BATCH * NLAT;

  char* ws = (char*)d_ws;
  unsigned short* W1B = (unsigned short*)ws;                          // 1 MB
  unsigned short* W2B = (unsigned short*)(ws + (1u << 20));           // 128 KB
  float* decT  = (float*)(ws + (1u << 20) + (1u << 17));              // 512 KB
  float* zsumg = (float*)(ws + (1u << 20) + (1u << 17) + (1u << 19)); // 1 MB

  prep_all<<<dim3(416), 256, 0, stream>>>(W1, W2, dec, W1B, W2B, decT);
  enc_kernel<<<dim3(BATCH / BM), 512, 0, stream>>>(x, W1B, W2B, b1, b2, zout, zsumg);
  recon_kernel<<<dim3(4096), 256, 0, stream>>>(zsumg, decT, rout);
}